// Round 15
// baseline (96.699 us; speedup 1.0000x reference)
//
#include <hip/hip_runtime.h>

// QueryAndGroup — test dims B=2, Nb=512, N=1024, M=64, K=216, C=32, ns=32.
// Inputs f32; OUTPUT f32: [group_features (L,3+C) | set_new_indices (L,)].
// Trajectory: 606 (fused, 32 blocks) -> 110 (3-kernel split) -> 109.6 (flat
// pairs) -> 318 (coop REGRESSION: grid.sync ~100us on 8 XCDs) -> 91.2
// (folded memset + recorded j's + gather-emit). Harness floor ~75 us (256 MB
// ws poison fill @41us + restore dispatches, inside timed window).
// Round-15: fold the scan INTO emit (every block redundantly scans counts[N]
// in LDS - 4 KB, L2-hot, idle CUs) -> 2 dispatches; float4 output zeroing.

#pragma clang fp contract(off)

typedef unsigned long long u64;

#define MAXN 4096

// ---- count: wave per row; float4 zero of output; x4-batched test; record j's
__global__ __launch_bounds__(256) void count_kernel(
    const float* __restrict__ xyz, const float* __restrict__ new_xyz,
    const float* __restrict__ rois, int* __restrict__ counts,
    int* __restrict__ ballidx, float4* __restrict__ out_vec4,
    int N, int Nb, int M, int K, int nsample, int totalOut4)
{
    __shared__ int plist[4][64];
    const int wave = threadIdx.x >> 6;
    const int lane = threadIdx.x & 63;
    const int r = blockIdx.x * 4 + wave;
    const u64 laneLt = (1ull << lane) - 1ull;

    // Zero the output with 16B stores (emit runs later in stream order).
    {
        const int gtid = blockIdx.x * 256 + threadIdx.x;
        const int gthreads = gridDim.x * 256;
        const float4 z = make_float4(0.f, 0.f, 0.f, 0.f);
        for (int i = gtid; i < totalOut4; i += gthreads) out_vec4[i] = z;
    }

    if (r >= N) return;

    const int b  = r / Nb;
    const float px = xyz[3 * r + 0];
    const float py = xyz[3 * r + 1];
    const float pz = xyz[3 * r + 2];

    bool pass = false;
    if (lane < M) {
        const float* rp = rois + (size_t)(b * M + lane) * 7;
        const float dx = rp[3], dy = rp[4], dz = rp[5];
        const float r2 = (dx * dx + dy * dy) + dz * dz;   // numpy association
        const float ex = px - rp[0], ey = py - rp[1], ez = pz - rp[2];
        pass = ((ex * ex + ey * ey) + ez * ez) <= r2;
    }
    const u64 roiMask = __ballot(pass);
    if (!roiMask) { if (lane == 0) counts[r] = 0; return; }
    if (pass) plist[wave][__popcll(roiMask & laneLt)] = lane;  // ascending m

    const int P = __popcll(roiMask);
    const int total = P * K;
    const float* nb_ = new_xyz + (size_t)(b * M * K) * 3;
    int* bi = ballidx + (size_t)r * nsample;

    int cnt = 0;
    for (int base = 0; base < total && cnt < nsample; base += 256) {
        bool match[4];
        int jj[4];
        #pragma unroll
        for (int u = 0; u < 4; u++) {          // issue all loads before ballots
            const int p = base + u * 64 + lane;
            match[u] = false; jj[u] = 0;
            if (p < total) {
                const int ri = p / K;
                const int k  = p - ri * K;
                const int j  = plist[wave][ri] * K + k;
                jj[u] = j;
                const float* gp = nb_ + (size_t)j * 3;
                const float ax = px - gp[0], ay = py - gp[1], az = pz - gp[2];
                match[u] = ((ax * ax + ay * ay) + az * az) <= 1.0f;
            }
        }
        #pragma unroll
        for (int u = 0; u < 4; u++) {
            const u64 mm = __ballot(match[u]);
            const int slot = cnt + __popcll(mm & laneLt);
            if (match[u] && slot < nsample) bi[slot] = jj[u];
            cnt += __popcll(mm);
        }
    }
    if (lane == 0) counts[r] = cnt > nsample ? nsample : cnt;
}

// ---- emit: per-block LDS scan of counts[N], then gather + coalesced writes --
__global__ __launch_bounds__(256) void emit_kernel(
    const float* __restrict__ xyz, const float* __restrict__ new_xyz,
    const float* __restrict__ features,
    const int* __restrict__ counts, const int* __restrict__ ballidx,
    float* __restrict__ out_feat, float* __restrict__ out_idx,
    int N, int Nb, int M, int K, int C, int nsample)
{
    __shared__ int offs[MAXN];      // exclusive offsets (16 KB)
    __shared__ int waveAux[4];

    const int t = threadIdx.x;
    const int wave = t >> 6;
    const int lane = t & 63;

    // Redundant per-block exclusive scan of counts[N] (L2-hot 4 KB).
    const int G = (N + 255) / 256;             // elems per thread (contiguous)
    const int start = t * G;
    int c[32];                                  // G <= 16 for N<=4096
    int s = 0;
    for (int i = 0; i < G; i++) {
        const int idx = start + i;
        c[i] = (idx < N) ? counts[idx] : 0;
        s += c[i];
    }
    int incl = s;
    #pragma unroll
    for (int d = 1; d < 64; d <<= 1) {
        int v = __shfl_up(incl, d, 64);
        if (lane >= d) incl += v;
    }
    if (lane == 63) waveAux[wave] = incl;
    __syncthreads();
    if (t == 0) {
        int acc = 0;
        #pragma unroll
        for (int w = 0; w < 4; w++) { int tmp = waveAux[w]; waveAux[w] = acc; acc += tmp; }
    }
    __syncthreads();
    int run = waveAux[wave] + incl - s;
    for (int i = 0; i < G; i++) {
        const int idx = start + i;
        if (idx < N) offs[idx] = run;
        run += c[i];
    }
    __syncthreads();

    // Emit this block's 4 rows (wave per row).
    const int r = blockIdx.x * 4 + wave;
    if (r >= N) return;
    const int cnt = counts[r];
    if (cnt <= 0) return;

    const int b  = r / Nb;
    const int MK = M * K;
    const int obase = offs[r];
    const int* bi = ballidx + (size_t)r * nsample;
    const float px = xyz[3 * r + 0];
    const float py = xyz[3 * r + 1];
    const float pz = xyz[3 * r + 2];
    const float* fr = features + (size_t)r * C;
    const float* nb_ = new_xyz + (size_t)b * MK * 3;
    const int W = 3 + C;

    float* dst = out_feat + (size_t)obase * W;
    const int tot = cnt * W;
    for (int idx = lane; idx < tot; idx += 64) {
        const int s2 = idx / W;
        const int cc = idx - s2 * W;
        const int j = bi[s2];
        float v;
        if (cc == 0)      v = px - nb_[(size_t)j * 3 + 0];
        else if (cc == 1) v = py - nb_[(size_t)j * 3 + 1];
        else if (cc == 2) v = pz - nb_[(size_t)j * 3 + 2];
        else              v = fr[cc - 3];
        dst[idx] = v;
    }
    for (int s2 = lane; s2 < cnt; s2 += 64)
        out_idx[obase + s2] = (float)(b * MK + bi[s2]);
}

extern "C" void kernel_launch(void* const* d_in, const int* in_sizes, int n_in,
                              void* d_out, int out_size, void* d_ws, size_t ws_size,
                              hipStream_t stream) {
    if (n_in < 5) return;

    // ---- Role assignment by SIZE (unique on the true test sizes). ----
    int bc = 0;
    for (int i = 1; i < n_in; i++) if (in_sizes[i] < in_sizes[bc]) bc = i;
    const int B = in_sizes[bc];
    if (B < 1) return;

    int xi = -1, nwi = -1, ri = -1, fi = -1;
    int N = 0, M = 0, K = 0, C = 0, nsample = 0;

    for (int rr = 0; rr < n_in && xi < 0; rr++) {
        if (rr == bc) continue;
        if (in_sizes[rr] % (7 * B)) continue;            // rois = B*M*7
        const int M_ = in_sizes[rr] / (7 * B);
        if (M_ < 1 || M_ > 64) continue;
        for (int xx = 0; xx < n_in && xi < 0; xx++) {
            if (xx == bc || xx == rr) continue;
            if (in_sizes[xx] % 3) continue;              // xyz = N*3
            const int N_ = in_sizes[xx] / 3;
            if (N_ < B || N_ % B || N_ > MAXN) continue;
            for (int nn = 0; nn < n_in && xi < 0; nn++) {
                if (nn == bc || nn == rr || nn == xx) continue;
                if (in_sizes[nn] % (3 * B * M_)) continue;   // new_xyz = B*M*K*3
                const int K_ = in_sizes[nn] / (3 * B * M_);
                if (K_ < 1) continue;
                for (int ff = 0; ff < n_in && xi < 0; ff++) {
                    if (ff == bc || ff == rr || ff == xx || ff == nn) continue;
                    if (in_sizes[ff] % N_) continue;         // features = N*C
                    const int C_ = in_sizes[ff] / N_;
                    if (C_ < 1) continue;
                    if (out_size % (4 + C_)) continue;       // out = L*(4+C) f32
                    const long long L_ = (long long)out_size / (4 + C_);
                    if (L_ % N_) continue;
                    const int ns = (int)(L_ / N_);
                    if (ns < 1 || ns > 1024) continue;
                    // emit scan holds G=ceil(N/256) counts in registers (<=16)
                    if ((N_ + 255) / 256 > 16) continue;
                    xi = xx; nwi = nn; ri = rr; fi = ff;
                    N = N_; M = M_; K = K_; C = C_; nsample = ns;
                }
            }
        }
    }
    if (xi < 0) return;

    const float* xyz      = (const float*)d_in[xi];
    const float* new_xyz  = (const float*)d_in[nwi];
    const float* rois     = (const float*)d_in[ri];
    const float* features = (const float*)d_in[fi];
    const int Nb = N / B;

    const size_t L      = (size_t)N * nsample;
    const size_t chunk0 = L * (size_t)(3 + C);
    const size_t totalOut = chunk0 + L;                 // 36L, divisible by 4

    float* out_feat = (float*)d_out;
    float* out_idx  = out_feat + chunk0;

    // ws: counts[N] + ballidx[N*ns]
    const size_t wsNeed = ((size_t)N + (size_t)N * nsample) * sizeof(int);
    if (ws_size < wsNeed) return;
    int* counts  = (int*)d_ws;
    int* ballidx = counts + N;

    const int blocks = (N + 3) / 4;   // one wave per row

    if (totalOut % 4 == 0) {
        count_kernel<<<blocks, 256, 0, stream>>>(
            xyz, new_xyz, rois, counts, ballidx, (float4*)d_out,
            N, Nb, M, K, nsample, (int)(totalOut / 4));
    } else {
        (void)hipMemsetAsync(d_out, 0, totalOut * sizeof(float), stream);
        count_kernel<<<blocks, 256, 0, stream>>>(
            xyz, new_xyz, rois, counts, ballidx, (float4*)d_out,
            N, Nb, M, K, nsample, 0);
    }
    emit_kernel<<<blocks, 256, 0, stream>>>(
        xyz, new_xyz, features, counts, ballidx,
        out_feat, out_idx, N, Nb, M, K, C, nsample);
}

// Round 16
// 90.793 us; speedup vs baseline: 1.0651x; 1.0651x over previous
//
#include <hip/hip_runtime.h>

// QueryAndGroup — test dims B=2, Nb=512, N=1024, M=64, K=216, C=32, ns=32.
// Inputs f32; OUTPUT f32: [group_features (L,3+C) | set_new_indices (L,)].
// FINAL (= round-14 kernel, proven 91.2 us, prediction-matched).
// Trajectory: 606 (fused 32-block) -> 110 (count/scan/emit split) -> 109.6
// (flat pairs) -> 318 (coop grid.sync REGRESSION ~100us/sync on 8 XCDs) ->
// 91.2 (folded output-zeroing, recorded j's, gather-emit) -> 96.7 (scan-fold
// REGRESSION: scratch-backed reg array + per-block serial scan) -> revert.
// Decomposition: ~75 us harness poison/restore floor (256 MB ws fill @41us,
// flushes L2 every iter) + ~16 us pipeline (3 launches + cold-latency chains).

#pragma clang fp contract(off)

typedef unsigned long long u64;

#define MAXN 4096

// ---- count: wave per row; zero-output slice; x4-batched test; record j's ----
__global__ __launch_bounds__(256) void count_kernel(
    const float* __restrict__ xyz, const float* __restrict__ new_xyz,
    const float* __restrict__ rois, int* __restrict__ counts,
    int* __restrict__ ballidx, float* __restrict__ out_all,
    int N, int Nb, int M, int K, int nsample, int totalOut)
{
    __shared__ int plist[4][64];
    const int wave = threadIdx.x >> 6;
    const int lane = threadIdx.x & 63;
    const int r = blockIdx.x * 4 + wave;
    const u64 laneLt = (1ull << lane) - 1ull;

    // Zero this block's slice of the output (folded memset; emit runs later
    // in stream order, so no race).
    {
        const int gtid = blockIdx.x * 256 + threadIdx.x;
        const int gthreads = gridDim.x * 256;
        for (int i = gtid; i < totalOut; i += gthreads) out_all[i] = 0.0f;
    }

    if (r >= N) return;

    const int b  = r / Nb;
    const float px = xyz[3 * r + 0];
    const float py = xyz[3 * r + 1];
    const float pz = xyz[3 * r + 2];

    bool pass = false;
    if (lane < M) {
        const float* rp = rois + (size_t)(b * M + lane) * 7;
        const float dx = rp[3], dy = rp[4], dz = rp[5];
        const float r2 = (dx * dx + dy * dy) + dz * dz;   // numpy association
        const float ex = px - rp[0], ey = py - rp[1], ez = pz - rp[2];
        pass = ((ex * ex + ey * ey) + ez * ez) <= r2;
    }
    const u64 roiMask = __ballot(pass);
    if (!roiMask) { if (lane == 0) counts[r] = 0; return; }
    if (pass) plist[wave][__popcll(roiMask & laneLt)] = lane;  // ascending m

    const int P = __popcll(roiMask);
    const int total = P * K;
    const float* nb_ = new_xyz + (size_t)(b * M * K) * 3;
    int* bi = ballidx + (size_t)r * nsample;

    int cnt = 0;
    for (int base = 0; base < total && cnt < nsample; base += 256) {
        bool match[4];
        int jj[4];
        #pragma unroll
        for (int u = 0; u < 4; u++) {          // issue all loads before ballots
            const int p = base + u * 64 + lane;
            match[u] = false; jj[u] = 0;
            if (p < total) {
                const int ri = p / K;
                const int k  = p - ri * K;
                const int j  = plist[wave][ri] * K + k;
                jj[u] = j;
                const float* gp = nb_ + (size_t)j * 3;
                const float ax = px - gp[0], ay = py - gp[1], az = pz - gp[2];
                match[u] = ((ax * ax + ay * ay) + az * az) <= 1.0f;
            }
        }
        #pragma unroll
        for (int u = 0; u < 4; u++) {
            const u64 mm = __ballot(match[u]);
            const int slot = cnt + __popcll(mm & laneLt);
            if (match[u] && slot < nsample) bi[slot] = jj[u];
            cnt += __popcll(mm);
        }
    }
    if (lane == 0) counts[r] = cnt > nsample ? nsample : cnt;
}

// ---- scan: exclusive scan of counts[N], N <= 4096, one block ----
__global__ __launch_bounds__(1024) void scan_kernel(
    const int* __restrict__ counts, int* __restrict__ offsets, int N)
{
    __shared__ int waveAux[16];
    const int t = threadIdx.x;
    const int lane = t & 63;
    const int wid = t >> 6;
    const int base = t * 4;
    int c[4];
    int s = 0;
    #pragma unroll
    for (int i = 0; i < 4; i++) {
        c[i] = (base + i < N) ? counts[base + i] : 0;
        s += c[i];
    }
    int incl = s;
    #pragma unroll
    for (int d = 1; d < 64; d <<= 1) {
        int v = __shfl_up(incl, d, 64);
        if (lane >= d) incl += v;
    }
    if (lane == 63) waveAux[wid] = incl;
    __syncthreads();
    if (t < 16) {
        int v = waveAux[t];
        #pragma unroll
        for (int d = 1; d < 16; d <<= 1) {
            int u = __shfl_up(v, d, 64);
            if (t >= d) v += u;
        }
        waveAux[t] = v;
    }
    __syncthreads();
    int run = (wid ? waveAux[wid - 1] : 0) + incl - s;
    #pragma unroll
    for (int i = 0; i < 4; i++) {
        if (base + i < N) offsets[base + i] = run;
        run += c[i];
    }
}

// ---- emit: wave per row; pure gather from ballidx; coalesced writes ----
__global__ __launch_bounds__(256) void emit_kernel(
    const float* __restrict__ xyz, const float* __restrict__ new_xyz,
    const float* __restrict__ features,
    const int* __restrict__ counts, const int* __restrict__ offsets,
    const int* __restrict__ ballidx,
    float* __restrict__ out_feat, float* __restrict__ out_idx,
    int N, int Nb, int M, int K, int C, int nsample)
{
    const int wave = threadIdx.x >> 6;
    const int lane = threadIdx.x & 63;
    const int r = blockIdx.x * 4 + wave;
    if (r >= N) return;

    const int cnt = counts[r];
    if (cnt <= 0) return;

    const int b  = r / Nb;
    const int MK = M * K;
    const int obase = offsets[r];
    const int* bi = ballidx + (size_t)r * nsample;
    const float px = xyz[3 * r + 0];
    const float py = xyz[3 * r + 1];
    const float pz = xyz[3 * r + 2];
    const float* fr = features + (size_t)r * C;
    const float* nb_ = new_xyz + (size_t)b * MK * 3;
    const int W = 3 + C;

    // Feature block: cnt*W contiguous floats at out_feat + obase*W.
    float* dst = out_feat + (size_t)obase * W;
    const int tot = cnt * W;
    for (int idx = lane; idx < tot; idx += 64) {
        const int s = idx / W;
        const int c = idx - s * W;
        const int j = bi[s];
        float v;
        if (c == 0)      v = px - nb_[(size_t)j * 3 + 0];
        else if (c == 1) v = py - nb_[(size_t)j * 3 + 1];
        else if (c == 2) v = pz - nb_[(size_t)j * 3 + 2];
        else             v = fr[c - 3];
        dst[idx] = v;
    }
    for (int s = lane; s < cnt; s += 64)
        out_idx[obase + s] = (float)(b * MK + bi[s]);
}

extern "C" void kernel_launch(void* const* d_in, const int* in_sizes, int n_in,
                              void* d_out, int out_size, void* d_ws, size_t ws_size,
                              hipStream_t stream) {
    if (n_in < 5) return;

    // ---- Role assignment by SIZE (unique on the true test sizes). ----
    int bc = 0;
    for (int i = 1; i < n_in; i++) if (in_sizes[i] < in_sizes[bc]) bc = i;
    const int B = in_sizes[bc];
    if (B < 1) return;

    int xi = -1, nwi = -1, ri = -1, fi = -1;
    int N = 0, M = 0, K = 0, C = 0, nsample = 0;

    for (int rr = 0; rr < n_in && xi < 0; rr++) {
        if (rr == bc) continue;
        if (in_sizes[rr] % (7 * B)) continue;            // rois = B*M*7
        const int M_ = in_sizes[rr] / (7 * B);
        if (M_ < 1 || M_ > 64) continue;
        for (int xx = 0; xx < n_in && xi < 0; xx++) {
            if (xx == bc || xx == rr) continue;
            if (in_sizes[xx] % 3) continue;              // xyz = N*3
            const int N_ = in_sizes[xx] / 3;
            if (N_ < B || N_ % B || N_ > MAXN) continue;
            for (int nn = 0; nn < n_in && xi < 0; nn++) {
                if (nn == bc || nn == rr || nn == xx) continue;
                if (in_sizes[nn] % (3 * B * M_)) continue;   // new_xyz = B*M*K*3
                const int K_ = in_sizes[nn] / (3 * B * M_);
                if (K_ < 1) continue;
                for (int ff = 0; ff < n_in && xi < 0; ff++) {
                    if (ff == bc || ff == rr || ff == xx || ff == nn) continue;
                    if (in_sizes[ff] % N_) continue;         // features = N*C
                    const int C_ = in_sizes[ff] / N_;
                    if (C_ < 1) continue;
                    if (out_size % (4 + C_)) continue;       // out = L*(4+C) f32
                    const long long L_ = (long long)out_size / (4 + C_);
                    if (L_ % N_) continue;
                    const int ns = (int)(L_ / N_);
                    if (ns < 1 || ns > 1024) continue;
                    xi = xx; nwi = nn; ri = rr; fi = ff;
                    N = N_; M = M_; K = K_; C = C_; nsample = ns;
                }
            }
        }
    }
    if (xi < 0) return;

    const float* xyz      = (const float*)d_in[xi];
    const float* new_xyz  = (const float*)d_in[nwi];
    const float* rois     = (const float*)d_in[ri];
    const float* features = (const float*)d_in[fi];
    const int Nb = N / B;

    const size_t L      = (size_t)N * nsample;
    const size_t chunk0 = L * (size_t)(3 + C);
    const int totalOut  = (int)(chunk0 + L);

    float* out_feat = (float*)d_out;
    float* out_idx  = out_feat + chunk0;

    // ws: counts[N] + offsets[N] + ballidx[N*ns]
    const size_t wsNeed = ((size_t)2 * N + (size_t)N * nsample) * sizeof(int);
    if (ws_size < wsNeed) return;
    int* counts  = (int*)d_ws;
    int* offsets = counts + N;
    int* ballidx = offsets + N;

    const int blocks = (N + 3) / 4;   // one wave per row

    count_kernel<<<blocks, 256, 0, stream>>>(
        xyz, new_xyz, rois, counts, ballidx, out_feat,
        N, Nb, M, K, nsample, totalOut);
    scan_kernel<<<1, 1024, 0, stream>>>(counts, offsets, N);
    emit_kernel<<<blocks, 256, 0, stream>>>(
        xyz, new_xyz, features, counts, offsets, ballidx,
        out_feat, out_idx, N, Nb, M, K, C, nsample);
}